// Round 15
// baseline (12195.663 us; speedup 1.0000x reference)
//
#include <hip/hip_runtime.h>
#include <hip/hip_bf16.h>

typedef __attribute__((ext_vector_type(8))) short bf16x8;
typedef __attribute__((ext_vector_type(4))) float f32x4;
typedef unsigned int u32t;

#define S_LEN 2048
#define BATCH 64
#define IDIM 256
#define HDIM 512
#define KDIM 768
#define ODIM 512
#define NGRP 4    // groups = XCDs 0..3, 16 batch rows each
#define NSLOT 32  // blocks per group, each owns 16 h-cols (4 waves x 4)
#define LDX 264   // x slab row stride (shorts)
#define XSLAB (16 * LDX)
#define FPAD 16           // ints per pair-flag line (64B)
#define POLL_CAP (1 << 16)

#define SMEM_BYTES 98304  // force 1 block/CU (placement determinism)

__device__ __forceinline__ unsigned short f2b(float f) {
  __hip_bfloat16 h = __float2bfloat16(f);
  return __builtin_bit_cast(unsigned short, h);
}
__device__ __forceinline__ float sigmoidf_(float x) { return 1.0f / (1.0f + __expf(-x)); }
__device__ __forceinline__ float tanhf_(float x) { return 1.0f - 2.0f / (1.0f + __expf(2.0f * x)); }

__device__ __forceinline__ bf16x8 cvt8(float4 v0, float4 v1) {
  bf16x8 b;
  b[0] = (short)f2b(v0.x); b[1] = (short)f2b(v0.y);
  b[2] = (short)f2b(v0.z); b[3] = (short)f2b(v0.w);
  b[4] = (short)f2b(v1.x); b[5] = (short)f2b(v1.y);
  b[6] = (short)f2b(v1.z); b[7] = (short)f2b(v1.w);
  return b;
}

// Fresh L2 read: atomics execute at the XCD L2 (no L0 RMW path). Opaque addend
// stops LLVM folding fetch_add(p,0) into a cacheable load. HW-validated r6-r14.
__device__ __forceinline__ int l2_read(int* p) {
  int z = 0;
  asm volatile("" : "+v"(z));
  return __hip_atomic_fetch_add(p, z, __ATOMIC_RELAXED, __HIP_MEMORY_SCOPE_WORKGROUP);
}

__global__ void lstm_init(const float* __restrict__ wh2o,
                          __hip_bfloat16* __restrict__ wh2o_bf,
                          __hip_bfloat16* __restrict__ h_all,
                          int* __restrict__ ctrl) {
  int idx = blockIdx.x * 256 + threadIdx.x;
  if (idx < ODIM * HDIM) wh2o_bf[idx] = __float2bfloat16(wh2o[idx]);
  if (idx < BATCH * HDIM) h_all[idx] = __float2bfloat16(0.0f);  // h(0) = 0
  if (idx < 131072) ctrl[idx] = 0;  // cnt + pair-flag matrix (512KB)
}

// ===== persistent recurrence: 4 XCD-local groups, pair-wise flag matrix =====
__global__ __launch_bounds__(256) void lstm_recur(
    const float* __restrict__ x,
    const float* __restrict__ Wi, const float* __restrict__ bi,
    const float* __restrict__ Wf, const float* __restrict__ bfp,
    const float* __restrict__ Wg, const float* __restrict__ bgp,
    const float* __restrict__ Wo, const float* __restrict__ bop,
    __hip_bfloat16* __restrict__ h_all, int* __restrict__ flags,
    int* __restrict__ cnt) {
  extern __shared__ char smem[];
  __shared__ int sel[2];
  const int tid = threadIdx.x;
  const int lane = tid & 63;

  if (tid == 0) {
    unsigned xcd;
    asm("s_getreg_b32 %0, hwreg(HW_REG_XCC_ID)" : "=s"(xcd));
    sel[0] = (int)(xcd & 7);
    sel[1] = atomicAdd(&cnt[(xcd & 7) * 16], 1);  // one-time, device scope
  }
  __syncthreads();
  const int g = sel[0];
  const int s = sel[1];
  if (g >= NGRP || s >= NSLOT) return;  // XCDs 4-7 + surplus blocks idle

  short* xsl = (short*)smem;  // [2][16][LDX] bf16 (only LDS use)

  const int wave = tid >> 6;  // 0..3
  // Wave's MFMA B-tile: 16 cols = {gate 0..3} x {h-col wave*4+q}, full K=768.
  const int bc = lane & 15;
  const int gate = bc >> 2;
  const int q = bc & 3;
  const int hi8 = (lane >> 4) * 8;  // K sub-slice

  // --- prologue: weight fragments fp32 -> bf16 registers ---
  const float* wsrc = (gate == 0) ? Wi : (gate == 1) ? Wf : (gate == 2) ? Wg : Wo;
  const float* wrow = wsrc + (size_t)(s * 16 + wave * 4 + q) * KDIM;
  bf16x8 bfr[24];  // 0..7 x-part (K 0..255), 8..23 h-part (K 256..767)
#pragma unroll
  for (int kk = 0; kk < 8; ++kk) {
    int k0 = kk * 32 + hi8;
    bfr[kk] = cvt8(*(const float4*)(wrow + k0), *(const float4*)(wrow + k0 + 4));
  }
#pragma unroll
  for (int kk = 8; kk < 24; ++kk) {
    int k0 = IDIM + (kk - 8) * 32 + hi8;
    bfr[kk] = cvt8(*(const float4*)(wrow + k0), *(const float4*)(wrow + k0 + 4));
  }
  const int hc_abs = s * 16 + wave * 4 + (lane & 3);
  const float bi_r = bi[hc_abs], bf_r = bfp[hc_abs], bg_r = bgp[hc_abs], bo_r = bop[hc_abs];

  // x pipeline: 2-step register lookahead (4 float4/thread at 256 threads)
  float4 rx[4];
  auto ldx = [&](int t) {
    const float4* xs = (const float4*)(x + ((size_t)t * BATCH + g * 16) * IDIM);
#pragma unroll
    for (int j = 0; j < 4; ++j) rx[j] = xs[tid + j * 256];
  };
  auto stx = [&](int par) {
#pragma unroll
    for (int j = 0; j < 4; ++j) {
      int i = tid + j * 256;
      int r = i >> 6, k4 = i & 63;
      float4 v = rx[j];
      ushort4 u;
      u.x = f2b(v.x); u.y = f2b(v.y); u.z = f2b(v.z); u.w = f2b(v.w);
      *(ushort4*)&xsl[par * XSLAB + r * LDX + k4 * 4] = u;
    }
  };

  // bootstrap: x(0) -> slab0 -> acc ; x(1) -> regs
  ldx(0);
  stx(0);
  __syncthreads();
  f32x4 c0 = {}, c1 = {};
  {
    const short* ax = &xsl[(lane & 15) * LDX + hi8];
#pragma unroll
    for (int kk = 0; kk < 8; kk += 2) {
      c0 = __builtin_amdgcn_mfma_f32_16x16x32_bf16(*(const bf16x8*)(ax + kk * 32),
                                                   bfr[kk], c0, 0, 0, 0);
      c1 = __builtin_amdgcn_mfma_f32_16x16x32_bf16(*(const bf16x8*)(ax + kk * 32 + 32),
                                                   bfr[kk + 1], c1, 0, 0, 0);
    }
  }
  ldx(1);

  float cst[4] = {0.f, 0.f, 0.f, 0.f};  // owner lanes: 4 rows x 1 h-col
  // Pair-wise flag matrix: line (producer=l, consumer=s) polled ONLY by block s.
  int* pollp = (lane < NSLOT)
                   ? flags + ((g * NSLOT + lane) * NSLOT + s) * FPAD
                   : nullptr;
  int* pubbase = flags + ((g * NSLOT + s) * NSLOT) * FPAD;  // my row: 32 lines

  for (int t = 0; t < S_LEN; ++t) {
    // --- A: per-wave gather of MY private flag column (zero contention) ---
    for (int it = 0; it < POLL_CAP; ++it) {
      int v = pollp ? l2_read(pollp) : 0x7fffffff;
      if (__all(v >= t)) break;
    }
    asm volatile("" ::: "memory");
    // --- B: h-part GEMM, A-frags direct from L2, 4 chains x 4 deep ---
    f32x4 h0 = {}, h1 = {};
    {
      const short* hb = (const short*)h_all +
                        ((size_t)t * BATCH + g * 16 + (lane & 15)) * HDIM + hi8;
#pragma unroll
      for (int kk = 0; kk < 16; kk += 4) {
        bf16x8 a0 = *(const bf16x8*)(hb + kk * 32);
        bf16x8 a1 = *(const bf16x8*)(hb + kk * 32 + 32);
        bf16x8 a2 = *(const bf16x8*)(hb + kk * 32 + 64);
        bf16x8 a3 = *(const bf16x8*)(hb + kk * 32 + 96);
        c0 = __builtin_amdgcn_mfma_f32_16x16x32_bf16(a0, bfr[8 + kk], c0, 0, 0, 0);
        c1 = __builtin_amdgcn_mfma_f32_16x16x32_bf16(a1, bfr[9 + kk], c1, 0, 0, 0);
        h0 = __builtin_amdgcn_mfma_f32_16x16x32_bf16(a2, bfr[10 + kk], h0, 0, 0, 0);
        h1 = __builtin_amdgcn_mfma_f32_16x16x32_bf16(a3, bfr[11 + kk], h1, 0, 0, 0);
      }
    }
    // --- C: in-wave gate combine + state update + packed publish ---
    {
      f32x4 av;
#pragma unroll
      for (int j = 0; j < 4; ++j) av[j] = (c0[j] + c1[j]) + (h0[j] + h1[j]);
      const int row0 = (lane >> 4) * 4;
      u32t* hw_base = (u32t*)((short*)h_all + (size_t)(t + 1) * BATCH * HDIM);
#pragma unroll
      for (int j = 0; j < 4; ++j) {
        float iv = av[j];
        float fv = __shfl(av[j], lane + 4);
        float gv = __shfl(av[j], lane + 8);
        float ov = __shfl(av[j], lane + 12);
        if ((lane & 12) == 0) {  // 16 owner lanes: col q, rows row0..row0+3
          float ig = sigmoidf_(bi_r + iv);
          float fg = sigmoidf_(bf_r + fv);
          float gg = tanhf_(bg_r + gv);
          float og = sigmoidf_(bo_r + ov);
          cst[j] = fg * cst[j] + ig * gg;
          float hv = og * tanhf_(cst[j]);
          float hvp = __shfl_xor(hv, 1);  // col partner (owner pairs 0-1, 2-3)
          if (!(lane & 1)) {
            u32t hw = (u32t)f2b(hv) | ((u32t)f2b(hvp) << 16);
            hw_base[((size_t)(g * 16 + row0 + j) * HDIM + hc_abs) >> 1] = hw;
          }
        }
      }
    }
    asm volatile("s_waitcnt vmcnt(0)" ::: "memory");  // h(t+1) acked at L2
    __syncthreads();                                  // whole block published
    if (tid < NSLOT)
      __hip_atomic_store(pubbase + tid * FPAD, t + 1, __ATOMIC_RELAXED,
                         __HIP_MEMORY_SCOPE_WORKGROUP);  // row broadcast: 32 lines
    // --- D (shadow): x slab handoff + x-part GEMM for t+1 + x(t+2) loads ---
    if (t + 1 < S_LEN) {
      stx((t + 1) & 1);
      __syncthreads();
      f32x4 z = {};
      c0 = z;
      c1 = z;
      const short* ax = &xsl[((t + 1) & 1) * XSLAB + (lane & 15) * LDX + hi8];
#pragma unroll
      for (int kk = 0; kk < 8; kk += 2) {
        c0 = __builtin_amdgcn_mfma_f32_16x16x32_bf16(*(const bf16x8*)(ax + kk * 32),
                                                     bfr[kk], c0, 0, 0, 0);
        c1 = __builtin_amdgcn_mfma_f32_16x16x32_bf16(*(const bf16x8*)(ax + kk * 32 + 32),
                                                     bfr[kk + 1], c1, 0, 0, 0);
      }
      ldx((t + 2 < S_LEN) ? t + 2 : S_LEN - 1);
    }
  }
}

// ===== output projection + log-softmax: massively parallel, after the scan =====
__global__ __launch_bounds__(256) void lstm_out(
    const __hip_bfloat16* __restrict__ h_all,
    const __hip_bfloat16* __restrict__ wh2o_bf, const float* __restrict__ bh2o,
    float* __restrict__ out) {
  const int t = blockIdx.x;
  const int tid = threadIdx.x;
  const int lane = tid & 63;
  const int wave = tid >> 6;
  const int r0 = wave * 16;
  const short* abase = (const short*)h_all +
                       ((size_t)(t + 1) * BATCH + r0 + (lane & 15)) * HDIM + (lane >> 4) * 8;
  const short* bbase = (const short*)wh2o_bf + (size_t)(lane & 15) * HDIM + (lane >> 4) * 8;
  f32x4 acc[32];
  f32x4 zero = {0.f, 0.f, 0.f, 0.f};
#pragma unroll
  for (int n = 0; n < 32; ++n) acc[n] = zero;
  for (int kk = 0; kk < 16; ++kk) {
    bf16x8 a = *(const bf16x8*)(abase + kk * 32);
#pragma unroll
    for (int n = 0; n < 32; ++n) {
      bf16x8 b = *(const bf16x8*)(bbase + (size_t)n * 16 * HDIM + kk * 32);
      acc[n] = __builtin_amdgcn_mfma_f32_16x16x32_bf16(a, b, acc[n], 0, 0, 0);
    }
  }
  float mx[4] = {-3.0e38f, -3.0e38f, -3.0e38f, -3.0e38f};
#pragma unroll
  for (int n = 0; n < 32; ++n) {
    float bn = bh2o[n * 16 + (lane & 15)];
#pragma unroll
    for (int j = 0; j < 4; ++j) {
      acc[n][j] += bn;
      mx[j] = fmaxf(mx[j], acc[n][j]);
    }
  }
#pragma unroll
  for (int j = 0; j < 4; ++j) {
    mx[j] = fmaxf(mx[j], __shfl_xor(mx[j], 1));
    mx[j] = fmaxf(mx[j], __shfl_xor(mx[j], 2));
    mx[j] = fmaxf(mx[j], __shfl_xor(mx[j], 4));
    mx[j] = fmaxf(mx[j], __shfl_xor(mx[j], 8));
  }
  float sm[4] = {0.f, 0.f, 0.f, 0.f};
#pragma unroll
  for (int n = 0; n < 32; ++n) {
#pragma unroll
    for (int j = 0; j < 4; ++j) sm[j] += __expf(acc[n][j] - mx[j]);
  }
#pragma unroll
  for (int j = 0; j < 4; ++j) {
    sm[j] += __shfl_xor(sm[j], 1);
    sm[j] += __shfl_xor(sm[j], 2);
    sm[j] += __shfl_xor(sm[j], 4);
    sm[j] += __shfl_xor(sm[j], 8);
  }
  float ls[4];
#pragma unroll
  for (int j = 0; j < 4; ++j) ls[j] = mx[j] + __logf(sm[j]);
  float* ob = out + (size_t)t * BATCH * ODIM;
#pragma unroll
  for (int n = 0; n < 32; ++n) {
#pragma unroll
    for (int j = 0; j < 4; ++j) {
      int row = r0 + (lane >> 4) * 4 + j;
      ob[(size_t)row * ODIM + n * 16 + (lane & 15)] = acc[n][j] - ls[j];
    }
  }
}

extern "C" void kernel_launch(void* const* d_in, const int* in_sizes, int n_in,
                              void* d_out, int out_size, void* d_ws, size_t ws_size,
                              hipStream_t stream) {
  const float* x = (const float*)d_in[0];
  const float* Wi = (const float*)d_in[1];
  const float* bi = (const float*)d_in[2];
  const float* Wf = (const float*)d_in[3];
  const float* bf = (const float*)d_in[4];
  const float* Wg = (const float*)d_in[5];
  const float* bg = (const float*)d_in[6];
  const float* Wo = (const float*)d_in[7];
  const float* bo = (const float*)d_in[8];
  const float* Wh2o = (const float*)d_in[9];
  const float* bh2o = (const float*)d_in[10];

  char* ws = (char*)d_ws;
  int* cnt = (int*)ws;                 // 8 XCD counters (padded), 16KB
  int* flags = (int*)(ws + 16384);     // [NGRP][NSLOT][NSLOT] 64B lines = 256KB
  __hip_bfloat16* h_all = (__hip_bfloat16*)(ws + 524288);  // [S+1][64][512]
  size_t h_all_b = (size_t)(S_LEN + 1) * BATCH * HDIM * 2;
  __hip_bfloat16* wh2o_bf = (__hip_bfloat16*)(ws + 524288 + h_all_b);
  size_t needed = 524288 + h_all_b + (size_t)ODIM * HDIM * 2;
  if (ws_size < needed || n_in < 11) return;

  hipFuncSetAttribute((const void*)lstm_recur,
                      hipFuncAttributeMaxDynamicSharedMemorySize, SMEM_BYTES);

  lstm_init<<<1024, 256, 0, stream>>>(Wh2o, wh2o_bf, h_all, (int*)ws);
  lstm_recur<<<256, 256, SMEM_BYTES, stream>>>(x, Wi, bi, Wf, bf, Wg, bg, Wo, bo,
                                               h_all, flags, cnt);
  lstm_out<<<S_LEN, 256, 0, stream>>>(h_all, wh2o_bf, bh2o, (float*)d_out);
}